// Round 10
// baseline (1347.326 us; speedup 1.0000x reference)
//
#include <hip/hip_runtime.h>

#define NEG_SLOPE 0.2f
#define FSHIFT 7            // fine bin = 128 rows
#define FROWS 128
#define MAXFINE 4096        // supports NT <= 524288 (actual NFINE = 2344)
#define CSHIFT 15           // coarse partition = 32768 rows = 256 fine bins
#define MAXP 16
#define EPB1 2048           // edges/block in bin_scatter
#define EPB2 4096           // edges/block in refine

// Combined destination space:
// rows [0,n0)=S0a(x0), [n0,2n0)=S0b(x1), [2n0,2n0+n3)=S3a(x3), [2n0+n3,NT)=S3b(x2)

__device__ __forceinline__ int decode_dst(int j, const int* ad0, const int* d1,
                                          const int* ad3, const int* d2,
                                          int E0, int E01, int E3,
                                          int n0, int n3) {
    if (j < E0) return ad0[j];
    if ((j -= E0) < E01) return n0 + d1[j];
    if ((j -= E01) < E3) return 2 * n0 + ad3[j];
    return 2 * n0 + n3 + d2[j - E3];
}

__device__ __forceinline__ int decode_src(int j, const int* as0, const int* s1,
                                          const int* as3, const int* s2,
                                          int E0, int E01, int E3) {
    if (j < E0) return as0[j];
    if ((j -= E0) < E01) return s1[j];
    if ((j -= E01) < E3) return as3[j];
    return s2[j - E3];
}

// fine-bin sizes: LDS hist per block, no-return global merge
__global__ __launch_bounds__(256) void fine_hist(const int* __restrict__ ad0,
                                                 const int* __restrict__ d1,
                                                 const int* __restrict__ ad3,
                                                 const int* __restrict__ d2,
                                                 int E0, int E01, int E3, int E23,
                                                 int n0, int n3, int NFINE,
                                                 int* __restrict__ fsizes) {
    __shared__ int h[MAXFINE];
    int t = threadIdx.x;
    for (int f = t; f < NFINE; f += 256) h[f] = 0;
    __syncthreads();
    int T = E0 + E01 + E3 + E23;
    int stride = gridDim.x * 256;
    for (int i = blockIdx.x * 256 + t; i < T; i += stride) {
        int cd = decode_dst(i, ad0, d1, ad3, d2, E0, E01, E3, n0, n3);
        atomicAdd(&h[cd >> FSHIFT], 1);
    }
    __syncthreads();
    for (int f = t; f < NFINE; f += 256)
        if (h[f]) atomicAdd(&fsizes[f], h[f]);   // no-return: fast
}

// single-block exclusive scan of fine sizes -> fstart, fine cursors, coarse cursors
__global__ __launch_bounds__(256) void scan_fine(const int* __restrict__ fsizes,
                                                 int NFINE, int NP, int E_total,
                                                 int* __restrict__ fstart,
                                                 int* __restrict__ fcursor4,
                                                 int* __restrict__ bcursor) {
    __shared__ int tsum[256];
    int t = threadIdx.x;
    int v[16];
    int s = 0;
#pragma unroll
    for (int j = 0; j < 16; ++j) {
        int f = t * 16 + j;
        v[j] = (f < NFINE) ? fsizes[f] : 0;
        s += v[j];
    }
    tsum[t] = s;
    __syncthreads();
    for (int off = 1; off < 256; off <<= 1) {
        int a = (t >= off) ? tsum[t - off] : 0;
        __syncthreads();
        tsum[t] += a;
        __syncthreads();
    }
    int run = tsum[t] - s;   // exclusive
#pragma unroll
    for (int j = 0; j < 16; ++j) {
        int f = t * 16 + j;
        if (f < NFINE) { fstart[f] = run; fcursor4[f * 4] = run; }
        run += v[j];
    }
    if (t == 0) fstart[NFINE] = E_total;
    __syncthreads();
    if (t < NP) bcursor[t] = fstart[t * 256];
}

// coarse binning: LDS hist + one reservation per (block,partition) + dense writes
__global__ __launch_bounds__(256) void bin_scatter(const int* __restrict__ ad0,
                                                   const int* __restrict__ as0,
                                                   const int* __restrict__ d1,
                                                   const int* __restrict__ s1,
                                                   const int* __restrict__ ad3,
                                                   const int* __restrict__ as3,
                                                   const int* __restrict__ d2,
                                                   const int* __restrict__ s2,
                                                   int E0, int E01, int E3, int E23,
                                                   int n0, int n3,
                                                   int* __restrict__ bcursor,
                                                   int2* __restrict__ bucket1) {
    __shared__ int h[MAXP], base[MAXP], loc[MAXP];
    int t = threadIdx.x;
    if (t < MAXP) { h[t] = 0; loc[t] = 0; }
    __syncthreads();

    int T = E0 + E01 + E3 + E23;
    int b0 = blockIdx.x * EPB1;
    int cd[EPB1 / 256], sv[EPB1 / 256];
    bool ok[EPB1 / 256];
#pragma unroll
    for (int j = 0; j < EPB1 / 256; ++j) {
        int idx = b0 + j * 256 + t;
        ok[j] = idx < T;
        if (ok[j]) {
            cd[j] = decode_dst(idx, ad0, d1, ad3, d2, E0, E01, E3, n0, n3);
            sv[j] = decode_src(idx, as0, s1, as3, s2, E0, E01, E3);
            atomicAdd(&h[cd[j] >> CSHIFT], 1);
        }
    }
    __syncthreads();
    if (t < MAXP && h[t] > 0) base[t] = atomicAdd(&bcursor[t], h[t]);
    __syncthreads();
#pragma unroll
    for (int j = 0; j < EPB1 / 256; ++j) {
        if (ok[j]) {
            int p = cd[j] >> CSHIFT;
            int o = atomicAdd(&loc[p], 1);
            bucket1[base[p] + o] = make_int2(cd[j], sv[j]);
        }
    }
}

// fine binning: chunk of bucket1 spans <=2 coarse partitions -> 512-bin LDS window
__global__ __launch_bounds__(256) void refine(const int2* __restrict__ bucket1,
                                              const int* __restrict__ fstart,
                                              int* __restrict__ fcursor4,
                                              int2* __restrict__ bucket2,
                                              int E_total, int NFINE, int NP) {
    __shared__ int h[512];
    int t = threadIdx.x;
    h[t] = 0;
    h[t + 256] = 0;
    int c0 = blockIdx.x * EPB2;
    int c1 = min(c0 + EPB2, E_total);
    int p0 = 0;
    for (int p = 1; p < NP; ++p)
        if (fstart[p * 256] <= c0) p0 = p;
    int wbase = p0 * 256;
    __syncthreads();
    for (int i = c0 + t; i < c1; i += 256) {
        int w = (bucket1[i].x >> FSHIFT) - wbase;
        if (w >= 0 && w < 512) atomicAdd(&h[w], 1);
    }
    __syncthreads();
    for (int w = t; w < 512; w += 256) {
        int c = h[w];
        if (c > 0 && wbase + w < NFINE)
            h[w] = atomicAdd(&fcursor4[(wbase + w) * 4], c);   // one returning atomic per (block,bin)
    }
    __syncthreads();
    for (int i = c0 + t; i < c1; i += 256) {
        int2 e = bucket1[i];
        int f = e.x >> FSHIFT;
        int w = f - wbase;
        int pos;
        if (w >= 0 && w < 512) pos = atomicAdd(&h[w], 1);      // LDS cursor
        else pos = atomicAdd(&fcursor4[f * 4], 1);             // slow path (never expected)
        bucket2[pos] = e;
    }
}

// one block per fine bin: LDS-accumulated gather, then full-line writeout.
// Rows with no edges get zeros (no agg memset needed anywhere).
__global__ __launch_bounds__(256) void gather_lds(const int2* __restrict__ bucket2,
                                                  const int* __restrict__ fstart,
                                                  const float* __restrict__ x0,
                                                  const float* __restrict__ x1,
                                                  const float* __restrict__ x2,
                                                  const float* __restrict__ x3,
                                                  float* __restrict__ agg0,
                                                  float* __restrict__ agg3,
                                                  int n0, int n3, int NT) {
    __shared__ float acc[FROWS * 64];   // 32 KB
    int t = threadIdx.x;
    for (int i = t; i < FROWS * 64; i += 256) acc[i] = 0.f;
    __syncthreads();

    int f = blockIdx.x;
    int beg = fstart[f], end = fstart[f + 1];
    int w = t >> 6, lane = t & 63;
    for (int i0 = beg + w * 4; i0 < end; i0 += 16) {
        int cnt = min(4, end - i0);
        int2 e[4];
        float v[4];
#pragma unroll
        for (int k = 0; k < 4; ++k)
            if (k < cnt) e[k] = bucket2[i0 + k];
#pragma unroll
        for (int k = 0; k < 4; ++k)
            if (k < cnt) {
                int cd = e[k].x, src = e[k].y;
                const float* xs = (cd < n0) ? x0
                                : (cd < 2 * n0) ? x1
                                : (cd < 2 * n0 + n3) ? x3 : x2;
                v[k] = xs[(size_t)src * 64 + lane];
            }
#pragma unroll
        for (int k = 0; k < 4; ++k)
            if (k < cnt) atomicAdd(&acc[(e[k].x & (FROWS - 1)) * 64 + lane], v[k]);
    }
    __syncthreads();

    int g = t >> 4, l = t & 15;
    for (int r = g; r < FROWS; r += 16) {
        int cd = f * FROWS + r;
        if (cd >= NT) break;
        float* dst;
        if (cd < n0)                dst = agg0 + (size_t)cd * 128;
        else if (cd < 2 * n0)       dst = agg0 + (size_t)(cd - n0) * 128 + 64;
        else if (cd < 2 * n0 + n3)  dst = agg3 + (size_t)(cd - 2 * n0) * 128;
        else                        dst = agg3 + (size_t)(cd - 2 * n0 - n3) * 128 + 64;
        *(float4*)&dst[l * 4] = *(float4*)&acc[r * 64 + l * 4];
    }
}

// combine_w2: WC0 = [W_hbs0 @ F0^T ; W_s01 @ F0^T], WC3 likewise; one launch.
__global__ __launch_bounds__(256) void combine_w2(const float* __restrict__ Wtop0,
                                                  const float* __restrict__ Wbot0,
                                                  const float* __restrict__ F0,
                                                  float* __restrict__ WC0,
                                                  const float* __restrict__ Wtop3,
                                                  const float* __restrict__ Wbot3,
                                                  const float* __restrict__ F3,
                                                  float* __restrict__ WC3) {
    int gi = blockIdx.x * 256 + threadIdx.x;   // 0..32767
    int which = gi >> 14;
    int i = gi & 16383;
    const float* Wtop = which ? Wtop3 : Wtop0;
    const float* Wbot = which ? Wbot3 : Wbot0;
    const float* F = which ? F3 : F0;
    float* WC = which ? WC3 : WC0;
    int k = i >> 7;
    int c = i & 127;
    const float* wrow = (k < 64) ? &Wtop[(size_t)k * 128] : &Wbot[(size_t)(k - 64) * 128];
    const float* frow = &F[(size_t)c * 128];
    float s = 0.f;
#pragma unroll 8
    for (int j = 0; j < 128; j += 4) {
        float4 w = *(const float4*)&wrow[j];
        float4 fv = *(const float4*)&frow[j];
        s = fmaf(w.x, fv.x, s);
        s = fmaf(w.y, fv.y, s);
        s = fmaf(w.z, fv.z, s);
        s = fmaf(w.w, fv.w, s);
    }
    WC[(size_t)k * 128 + c] = s;
}

// fc_lrelu: Y[n x 128] = lrelu(A[n x 128] @ WC + b); WC k-major.
__global__ __launch_bounds__(256) void fc_lrelu(const float* __restrict__ A,
                                                const float* __restrict__ WC,
                                                const float* __restrict__ bias,
                                                float* __restrict__ Y, int n) {
    __shared__ float WS[64][128];
    __shared__ float XS[64][68];
    const int t = threadIdx.x;
    const int row0 = blockIdx.x * 64;
    const int c = (t & 31) * 4;
    const int rbase = (t >> 5) * 8;
    float acc[8][4];
#pragma unroll
    for (int i = 0; i < 8; ++i)
#pragma unroll
        for (int j = 0; j < 4; ++j) acc[i][j] = 0.f;

    for (int p = 0; p < 2; ++p) {
        __syncthreads();
        const float4* Wp4 = (const float4*)(WC + (size_t)p * 64 * 128);
        float4* WS4 = (float4*)&WS[0][0];
        for (int i = t; i < 2048; i += 256) WS4[i] = Wp4[i];
        for (int i = t; i < 64 * 16; i += 256) {
            int r = i >> 4, c4 = i & 15;
            float4 v = make_float4(0.f, 0.f, 0.f, 0.f);
            if (row0 + r < n)
                v = *(const float4*)&A[(size_t)(row0 + r) * 128 + p * 64 + c4 * 4];
            *(float4*)&XS[r][c4 * 4] = v;
        }
        __syncthreads();

#pragma unroll 4
        for (int k = 0; k < 64; k += 4) {
            float4 w[4];
            w[0] = *(const float4*)&WS[k + 0][c];
            w[1] = *(const float4*)&WS[k + 1][c];
            w[2] = *(const float4*)&WS[k + 2][c];
            w[3] = *(const float4*)&WS[k + 3][c];
#pragma unroll
            for (int i = 0; i < 8; ++i) {
                float4 x = *(const float4*)&XS[rbase + i][k];
                float xs[4] = {x.x, x.y, x.z, x.w};
#pragma unroll
                for (int kk = 0; kk < 4; ++kk) {
                    acc[i][0] = fmaf(xs[kk], w[kk].x, acc[i][0]);
                    acc[i][1] = fmaf(xs[kk], w[kk].y, acc[i][1]);
                    acc[i][2] = fmaf(xs[kk], w[kk].z, acc[i][2]);
                    acc[i][3] = fmaf(xs[kk], w[kk].w, acc[i][3]);
                }
            }
        }
    }

    float4 b = *(const float4*)&bias[c];
    float bs[4] = {b.x, b.y, b.z, b.w};
#pragma unroll
    for (int i = 0; i < 8; ++i) {
        int r = row0 + rbase + i;
        if (r < n) {
            float o[4];
#pragma unroll
            for (int j = 0; j < 4; ++j) {
                float v = acc[i][j] + bs[j];
                o[j] = v > 0.f ? v : NEG_SLOPE * v;
            }
            *(float4*)&Y[(size_t)r * 128 + c] = make_float4(o[0], o[1], o[2], o[3]);
        }
    }
}

// one kernel for all three passthrough copies (float4 granularity)
__global__ __launch_bounds__(256) void copy_all(const float4* __restrict__ s1, float4* __restrict__ o1, int m1,
                                                const float4* __restrict__ s2, float4* __restrict__ o2, int m2,
                                                const float4* __restrict__ s4, float4* __restrict__ o4, int m4) {
    int total = m1 + m2 + m4;
    int i = blockIdx.x * 256 + threadIdx.x;
    int stride = gridDim.x * 256;
    for (; i < total; i += stride) {
        int j = i;
        if (j < m1) { o1[j] = s1[j]; }
        else if ((j -= m1) < m2) { o2[j] = s2[j]; }
        else { j -= m2; o4[j] = s4[j]; }
    }
}

extern "C" void kernel_launch(void* const* d_in, const int* in_sizes, int n_in,
                              void* d_out, int out_size, void* d_ws, size_t ws_size,
                              hipStream_t stream) {
    const float* x0 = (const float*)d_in[0];
    const float* x1 = (const float*)d_in[1];
    const float* x2 = (const float*)d_in[2];
    const float* x3 = (const float*)d_in[3];
    const float* x4 = (const float*)d_in[4];
    const int* adj0 = (const int*)d_in[5];
    const int* adj3 = (const int*)d_in[6];
    const int* inc01_t = (const int*)d_in[7];
    const int* inc01_s = (const int*)d_in[8];
    const int* inc23_t = (const int*)d_in[9];
    const int* inc23_s = (const int*)d_in[10];
    const float* W_hbs0 = (const float*)d_in[11];
    const float* W_hbs3 = (const float*)d_in[12];
    const float* W_s01 = (const float*)d_in[13];
    const float* W_t23 = (const float*)d_in[14];
    const float* fc0_W = (const float*)d_in[15];
    const float* fc0_b = (const float*)d_in[16];
    const float* fc3_W = (const float*)d_in[17];
    const float* fc3_b = (const float*)d_in[18];

    const int n0 = in_sizes[0] / 64, n1 = in_sizes[1] / 64;
    const int n2 = in_sizes[2] / 64, n3 = in_sizes[3] / 64, n4 = in_sizes[4] / 64;
    const int E0 = in_sizes[5] / 2, E3 = in_sizes[6] / 2;
    const int E01 = in_sizes[7], E23 = in_sizes[9];
    const int NT = 2 * n0 + 2 * n3;
    const int E_total = E0 + E01 + E3 + E23;
    const int NFINE = (NT + FROWS - 1) >> FSHIFT;
    const int NP = (NT + (1 << CSHIFT) - 1) >> CSHIFT;

    // workspace layout
    float* ws = (float*)d_ws;
    size_t off = 0;
    float* agg0 = ws + off; off += (size_t)n0 * 128;
    float* agg3 = ws + off; off += (size_t)n3 * 128;
    float* wc0 = ws + off;  off += 16384;
    float* wc3 = ws + off;  off += 16384;
    int* fsizes = (int*)(ws + off);   off += MAXFINE;
    int* fstart = (int*)(ws + off);   off += MAXFINE + 1;
    int* fcursor4 = (int*)(ws + off); off += (size_t)MAXFINE * 4;
    int* bcursor = (int*)(ws + off);  off += MAXP;
    off = (off + 1) & ~(size_t)1;                         // 8B align for int2
    int2* bucket1 = (int2*)(ws + off); off += (size_t)E_total * 2;
    int2* bucket2 = (int2*)(ws + off); off += (size_t)E_total * 2;

    float* out = (float*)d_out;
    float* o_x0 = out;
    float* o_x1 = o_x0 + (size_t)n0 * 128;
    float* o_x2 = o_x1 + (size_t)n1 * 64;
    float* o_x3 = o_x2 + (size_t)n2 * 64;
    float* o_x4 = o_x3 + (size_t)n3 * 128;

    // ---- two-level binning (all per-edge ordering via LDS cursors) ----
    hipMemsetAsync(fsizes, 0, (size_t)MAXFINE * sizeof(int), stream);
    fine_hist<<<128, 256, 0, stream>>>(adj0, inc01_t, adj3, inc23_s,
                                       E0, E01, E3, E23, n0, n3, NFINE, fsizes);
    scan_fine<<<1, 256, 0, stream>>>(fsizes, NFINE, NP, E_total,
                                     fstart, fcursor4, bcursor);
    bin_scatter<<<(E_total + EPB1 - 1) / EPB1, 256, 0, stream>>>(
        adj0, adj0 + E0, inc01_t, inc01_s, adj3, adj3 + E3, inc23_s, inc23_t,
        E0, E01, E3, E23, n0, n3, bcursor, bucket1);
    refine<<<(E_total + EPB2 - 1) / EPB2, 256, 0, stream>>>(
        bucket1, fstart, fcursor4, bucket2, E_total, NFINE, NP);

    // ---- LDS-accumulated gather (writes agg0/agg3 fully, zeros included) ----
    gather_lds<<<NFINE, 256, 0, stream>>>(bucket2, fstart, x0, x1, x2, x3,
                                          agg0, agg3, n0, n3, NT);

    // ---- combined weights + fused FC ----
    combine_w2<<<128, 256, 0, stream>>>(W_hbs0, W_s01, fc0_W, wc0,
                                        W_hbs3, W_t23, fc3_W, wc3);
    fc_lrelu<<<(n0 + 63) / 64, 256, 0, stream>>>(agg0, wc0, fc0_b, o_x0, n0);
    fc_lrelu<<<(n3 + 63) / 64, 256, 0, stream>>>(agg3, wc3, fc3_b, o_x3, n3);

    // ---- passthrough outputs (one kernel) ----
    copy_all<<<8192, 256, 0, stream>>>((const float4*)x1, (float4*)o_x1, n1 * 16,
                                       (const float4*)x2, (float4*)o_x2, n2 * 16,
                                       (const float4*)x4, (float4*)o_x4, n4 * 16);
}